// Round 7
// baseline (670.835 us; speedup 1.0000x reference)
//
#include <hip/hip_runtime.h>

// HPCrnn R7: R6 structure (16-row blocks, 2 blocks/CU, i8 MFMA weights in
// regs) + VALU diet: sigmoid via deg-7 odd polynomial (arg provably in
// [0,2.56] since Wap>=0, ec3 in [0,1]; tanh-form err <= 3e-4) written as
// float4 ext-vector math -> v_pk_*_f32 packed ops; table folds (Ev2=ev+.5av,
// f2 premultiplied, E3 state pre-scaled by 127). Transcendentals/step: 0.

typedef int   i32x4 __attribute__((ext_vector_type(4)));
typedef float f32x4 __attribute__((ext_vector_type(4)));

// tanh(u) ~= u*(C1 + C3 u^2 + C5 u^4 + C7 u^6) on [0,1.3]; sigma = .5 + .5*tanh(x/2)
#define D1 0.4995635f
#define D3 (-0.1614085f)
#define D5 0.0511812f
#define D7 (-0.0086042f)

// ---------- pre 1: weight absmax (signed atomicMax over 0xAA poison is safe) ----------
__global__ void wmax_kernel(const float* __restrict__ Wap, const float* __restrict__ Wc,
                            int* __restrict__ scaleWS) {
    const int i = blockIdx.x * 256 + threadIdx.x;
    float m1 = fabsf(Wap[i]);
    float m2 = fabsf(Wc[i]);
    #pragma unroll
    for (int o = 1; o < 64; o <<= 1) {
        m1 = fmaxf(m1, __shfl_xor(m1, o));
        m2 = fmaxf(m2, __shfl_xor(m2, o));
    }
    __shared__ float r1[4], r2[4];
    const int wv = threadIdx.x >> 6, ln = threadIdx.x & 63;
    if (ln == 0) { r1[wv] = m1; r2[wv] = m2; }
    __syncthreads();
    if (threadIdx.x == 0) {
        const float a = fmaxf(fmaxf(r1[0], r1[1]), fmaxf(r1[2], r1[3]));
        const float b = fmaxf(fmaxf(r2[0], r2[1]), fmaxf(r2[2], r2[3]));
        atomicMax(&scaleWS[0], __float_as_int(a));   // poison 0xAA.. is negative
        atomicMax(&scaleWS[1], __float_as_int(b));
    }
}

// ---------- pre 2: basal tables (needs scaleWS -> runs after wmax) ----------
__global__ void basal2_kernel(const float* __restrict__ Wbasal,
                              const float* __restrict__ bias,
                              const int* __restrict__ scaleWS,
                              float* __restrict__ Atab, float* __restrict__ E2tab,
                              float* __restrict__ ctab, float* __restrict__ ftab) {
    const int t = blockIdx.x, n = threadIdx.x;
    __shared__ float ca3s[256], red[256];
    const float x = (float)(t + 1);
    const float c0 = (float)n * (100.0f / 255.0f);
    const float d = (x - c0) * 0.2f;
    ca3s[n] = expf(-0.5f * d * d);
    __syncthreads();
    float bas = 0.f;
    #pragma unroll 8
    for (int k = 0; k < 256; ++k) bas += ca3s[k] * Wbasal[k * 256 + n];
    red[n] = bas;
    __syncthreads();
    for (int s = 128; s > 0; s >>= 1) {
        if (n < s) red[n] = fmaxf(red[n], red[n + s]);
        __syncthreads();
    }
    const float bmax = red[0];
    const float cq = 126.0f / (2.0f * bmax);       // q(ca1) < 127.5 guaranteed
    const float ct = (2.0f * bmax) / 126.0f;       // 1/cq
    Atab[t * 256 + n]  = bas * cq;                               // av
    E2tab[t * 256 + n] = (1.5f * bas - bias[n]) * cq + 0.5f;     // ev + 0.5*av (+rounding)
    if (n == 0) {
        ctab[t] = ct;
        ftab[t] = ct * __int_as_float(scaleWS[1]) / 127.0f;      // GEMM2 dequant, folded
    }
}

// ---------- pre 3: quantize weights to i8, transposed to [m][k] ----------
__global__ void wquant_kernel(const float* __restrict__ Wap, const float* __restrict__ Wc,
                              const int* __restrict__ scaleWS,
                              char* __restrict__ qWap, char* __restrict__ qWc) {
    const int m = blockIdx.x, k = threadIdx.x;
    const float q1 = 127.0f / __int_as_float(scaleWS[0]);
    const float q2 = 127.0f / __int_as_float(scaleWS[1]);
    qWap[m * 256 + k] = (char)(int)rintf(Wap[k * 256 + m] * q1);
    qWc[m * 256 + k]  = (char)(int)rintf(Wc[k * 256 + m] * q2);
}

// ---------- main: 16 rows/block, 8 waves, 2 barriers/step, 2 blocks/CU ----------
__global__ __launch_bounds__(512, 4) void rnn_kernel(
    const float* __restrict__ cue, const float* __restrict__ ec5_init,
    const char* __restrict__ qWap, const char* __restrict__ qWc,
    const int* __restrict__ scaleWS, const float* __restrict__ Wact,
    const float* __restrict__ Atab, const float* __restrict__ E2tab,
    const float* __restrict__ ctab, const float* __restrict__ ftab,
    float* __restrict__ out)
{
    __shared__ __align__(16) char sStage[8192 + 1024];  // sE@0, sC@4096, sPart@8192
    float* sPart = (float*)&sStage[8192];

    const int tid  = threadIdx.x;
    const int wave = tid >> 6;
    const int lane = tid & 63;
    const int quad = lane >> 4;
    const int L    = lane & 15;
    const int wb   = wave * 32;
    const int row0 = blockIdx.x * 16;

    // sigmoid poly arg scale: u = acc * sW1/(2*127*127)
    const float h = __int_as_float(scaleWS[0]) * (1.0f / 32258.0f);

    // weight A-frags: lane (quad,L) holds W^T[m=wb+mt*16+L][k=c*64+quad*16+j]
    i32x4 WA[2][4], WC[2][4];
    #pragma unroll
    for (int mt = 0; mt < 2; ++mt) {
        const int m = wb + mt * 16 + L;
        #pragma unroll
        for (int c = 0; c < 4; ++c) {
            WA[mt][c] = *(const i32x4*)&qWap[m * 256 + c * 64 + quad * 16];
            WC[mt][c] = *(const i32x4*)&qWc[m * 256 + c * 64 + quad * 16];
        }
    }

    // state: e5 (fp32), E3 = 127*ec3 (pre-scaled); C/D layout rows L, feats wb+mt*16+quad*4+r
    f32x4 e5v[2], E3v[2];
    #pragma unroll
    for (int mt = 0; mt < 2; ++mt) {
        e5v[mt] = *(const f32x4*)&ec5_init[(row0 + L) * 256 + wb + mt * 16 + quad * 4];
        E3v[mt] = f32x4{0.f, 0.f, 0.f, 0.f};
    }

    // XOR-swizzled stage addresses
    int rd[4], wr[2];
    #pragma unroll
    for (int c = 0; c < 4; ++c)
        rd[c] = L * 256 + (((4 * c + quad) ^ L) << 4);
    #pragma unroll
    for (int mt = 0; mt < 2; ++mt)
        wr[mt] = L * 256 + (((wave * 2 + mt) ^ L) << 4) + quad * 4;

    auto gemm = [&](int sb, const i32x4 (&W)[2][4], i32x4 (&acc)[2]) {
        #pragma unroll
        for (int c = 0; c < 4; ++c) {
            const i32x4 bf = *(const i32x4*)&sStage[sb + rd[c]];
            acc[0] = __builtin_amdgcn_mfma_i32_16x16x64_i8(W[0][c], bf, acc[0], 0, 0, 0);
            acc[1] = __builtin_amdgcn_mfma_i32_16x16x64_i8(W[1][c], bf, acc[1], 0, 0, 0);
        }
    };
    auto sigT = [&](const i32x4& a) -> f32x4 {   // T = sigmoid(f1*acc) - 0.5, via odd poly
        f32x4 y;
        #pragma unroll
        for (int r = 0; r < 4; ++r) y[r] = (float)a[r];
        const f32x4 u = y * h;
        const f32x4 w = u * u;
        f32x4 p = w * D7 + D5;
        p = p * w + D3;
        p = p * w + D1;
        return u * p;
    };

    // ===== t = 0 (peeled): ec3=0 -> T=0 -> stage value = max(Ev2, 0) =====
    {
        #pragma unroll
        for (int mt = 0; mt < 2; ++mt) {
            const f32x4 ev = *(const f32x4*)&E2tab[wb + mt * 16 + quad * 4];
            unsigned dw = 0;
            #pragma unroll
            for (int r = 0; r < 4; ++r)
                dw |= ((unsigned)fmaxf(ev[r], 0.0f)) << (8 * r);
            *(unsigned*)&sStage[4096 + wr[mt]] = dw;
        }
        __syncthreads();
        const float f2 = ftab[0];
        i32x4 acc2[2] = {};
        gemm(4096, WC, acc2);
        #pragma unroll
        for (int mt = 0; mt < 2; ++mt) {
            const f32x4 cv = *(const f32x4*)&cue[(row0 + L) * 256 + wb + mt * 16 + quad * 4];
            f32x4 y;
            #pragma unroll
            for (int r = 0; r < 4; ++r) y[r] = (float)acc2[mt][r];
            f32x4 n5 = y * f2 + e5v[mt];
            f32x4 E3;
            unsigned dw = 0;
            #pragma unroll
            for (int r = 0; r < 4; ++r) {
                n5[r] = __builtin_amdgcn_fmed3f(n5[r], 0.0f, 1.0f);
                E3[r] = __builtin_amdgcn_fmed3f(cv[r], 0.0f, 1.0f) * 127.0f;  // ec3_prev=0
                dw |= ((unsigned)(E3[r] + 0.5f)) << (8 * r);
            }
            e5v[mt] = n5; E3v[mt] = E3;
            *(unsigned*)&sStage[wr[mt]] = dw;
        }
        __syncthreads();
    }

    // ===== steady state t = 1..98: 2 phases, 2 barriers =====
    for (int t = 1; t <= 98; ++t) {
        f32x4 avc[2], evc[2];
        #pragma unroll
        for (int mt = 0; mt < 2; ++mt) {
            const int f0 = t * 256 + wb + mt * 16 + quad * 4;
            avc[mt] = *(const f32x4*)&Atab[f0];
            evc[mt] = *(const f32x4*)&E2tab[f0];
        }
        const float f2 = ftab[t];

        // Phase A: G1 + e1 (poly sigmoid, packed math) -> sC
        i32x4 acc[2] = {};
        gemm(0, WA, acc);
        #pragma unroll
        for (int mt = 0; mt < 2; ++mt) {
            const f32x4 T = sigT(acc[mt]);
            const f32x4 v = T * avc[mt] + evc[mt];
            unsigned dw = 0;
            #pragma unroll
            for (int r = 0; r < 4; ++r)
                dw |= ((unsigned)fmaxf(v[r], 0.0f)) << (8 * r);
            *(unsigned*)&sStage[4096 + wr[mt]] = dw;
        }
        __syncthreads();

        // Phase B: G2 + e2 -> sE (state update; E3 stays 127-scaled)
        i32x4 acc2[2] = {};
        gemm(4096, WC, acc2);
        #pragma unroll
        for (int mt = 0; mt < 2; ++mt) {
            f32x4 y;
            #pragma unroll
            for (int r = 0; r < 4; ++r) y[r] = (float)acc2[mt][r];
            f32x4 n5 = y * f2 + e5v[mt];
            #pragma unroll
            for (int r = 0; r < 4; ++r)
                n5[r] = __builtin_amdgcn_fmed3f(n5[r], 0.0f, 1.0f);
            const f32x4 n3s = n5 * E3v[mt];     // both factors >=0; product of [0,1]x[0,127]
            e5v[mt] = n5; E3v[mt] = n3s;
            const f32x4 q = n3s + 0.5f;
            unsigned dw = 0;
            #pragma unroll
            for (int r = 0; r < 4; ++r)
                dw |= ((unsigned)q[r]) << (8 * r);
            *(unsigned*)&sStage[wr[mt]] = dw;
        }
        __syncthreads();
    }

    // ===== t = 99 (peeled): G1 + e1(true scale) + Waction partial dot =====
    {
        i32x4 acc[2] = {};
        gemm(0, WA, acc);
        const float ct = ctab[99];
        float p0 = 0.f, p1 = 0.f;
        #pragma unroll
        for (int mt = 0; mt < 2; ++mt) {
            const int f0 = wb + mt * 16 + quad * 4;
            const f32x4 av = *(const f32x4*)&Atab[99 * 256 + f0];
            const f32x4 ev = *(const f32x4*)&E2tab[99 * 256 + f0];
            const f32x4 w0 = *(const f32x4*)&Wact[f0 * 2];
            const f32x4 w1 = *(const f32x4*)&Wact[f0 * 2 + 4];
            const f32x4 T = sigT(acc[mt]);
            const f32x4 v = T * av + ev;
            #pragma unroll
            for (int r = 0; r < 4; ++r) {
                const float c = fmaxf(v[r] - 0.5f, 0.0f) * ct;
                const float wa  = (r & 2) ? ((r & 1) ? w1[2] : w1[0]) : ((r & 1) ? w0[2] : w0[0]);
                const float wb2 = (r & 2) ? ((r & 1) ? w1[3] : w1[1]) : ((r & 1) ? w0[3] : w0[1]);
                p0 = fmaf(c, wa, p0);
                p1 = fmaf(c, wb2, p1);
            }
        }
        p0 += __shfl_xor(p0, 16); p0 += __shfl_xor(p0, 32);
        p1 += __shfl_xor(p1, 16); p1 += __shfl_xor(p1, 32);
        if (quad == 0) {
            sPart[(L * 2 + 0) * 8 + wave] = p0;
            sPart[(L * 2 + 1) * 8 + wave] = p1;
        }
    }
    __syncthreads();
    if (tid < 32) {
        float s = 0.f;
        #pragma unroll
        for (int g = 0; g < 8; ++g) s += sPart[tid * 8 + g];
        out[row0 * 2 + tid] = s;
    }
}

extern "C" void kernel_launch(void* const* d_in, const int* in_sizes, int n_in,
                              void* d_out, int out_size, void* d_ws, size_t ws_size,
                              hipStream_t stream) {
    const float* cue      = (const float*)d_in[0];
    const float* ec5_init = (const float*)d_in[1];
    const float* Wapical  = (const float*)d_in[2];
    const float* Wbasal   = (const float*)d_in[3];
    const float* Wca1ec5  = (const float*)d_in[4];
    const float* Waction  = (const float*)d_in[5];
    const float* ca1bias  = (const float*)d_in[6];
    float* out = (float*)d_out;

    float* Atab  = (float*)d_ws;                 // 25600 f32
    float* E2tab = Atab + 25600;                 // 25600 f32
    float* ctab  = E2tab + 25600;                // 100 f32
    float* ftab  = ctab + 100;                   // 100 f32
    int*   scaleWS = (int*)(ftab + 100);         // 4 ints (16B-aligned)
    char*  qWap = (char*)(scaleWS + 4);          // 65536 B
    char*  qWc  = qWap + 65536;                  // 65536 B

    wmax_kernel<<<256, 256, 0, stream>>>(Wapical, Wca1ec5, scaleWS);
    basal2_kernel<<<100, 256, 0, stream>>>(Wbasal, ca1bias, scaleWS, Atab, E2tab, ctab, ftab);
    wquant_kernel<<<256, 256, 0, stream>>>(Wapical, Wca1ec5, scaleWS, qWap, qWc);
    rnn_kernel<<<2048, 512, 0, stream>>>(cue, ec5_init, qWap, qWc, scaleWS, Waction,
                                         Atab, E2tab, ctab, ftab, out);
}

// Round 8
// 618.589 us; speedup vs baseline: 1.0845x; 1.0845x over previous
//
#include <hip/hip_runtime.h>

// HPCrnn R8: R6 structure verbatim (measured best: 622 us; exp sigmoid beat
// the R7 poly in-structure) + three safe deltas:
//  - kZero: first MFMA uses a persistent zero C-quad (kills accvgpr zero-init)
//  - desync: odd (blockIdx>>8) blocks sleep ~2k cyc once, anti-phasing the two
//    co-resident blocks' barrier drains (fills post-barrier bubbles)
//  - t-loop unroll x2 (98 iters = 49 pairs)
// i8 16x16x64 MFMA, weights register-resident, 16-row blocks, 2 blocks/CU.

typedef int   i32x4 __attribute__((ext_vector_type(4)));
typedef float f32x4 __attribute__((ext_vector_type(4)));

// ---------- pre 1: basal tables + zero scale slots ----------
__global__ void basal2_kernel(const float* __restrict__ Wbasal,
                              const float* __restrict__ bias,
                              float* __restrict__ Atab, float* __restrict__ Etab,
                              float* __restrict__ ctab, int* __restrict__ scaleWS) {
    const int t = blockIdx.x, n = threadIdx.x;
    __shared__ float ca3s[256], red[256];
    const float x = (float)(t + 1);
    const float c0 = (float)n * (100.0f / 255.0f);
    const float d = (x - c0) * 0.2f;
    ca3s[n] = expf(-0.5f * d * d);
    __syncthreads();
    float bas = 0.f;
    #pragma unroll 8
    for (int k = 0; k < 256; ++k) bas += ca3s[k] * Wbasal[k * 256 + n];
    red[n] = bas;
    __syncthreads();
    for (int s = 128; s > 0; s >>= 1) {
        if (n < s) red[n] = fmaxf(red[n], red[n + s]);
        __syncthreads();
    }
    const float bmax = red[0];
    const float cq = 126.0f / (2.0f * bmax);   // headroom so q(ca1) < 127.5
    Atab[t * 256 + n] = bas * cq;
    Etab[t * 256 + n] = (bas - bias[n]) * cq + 0.5f;   // +0.5 folds rounding
    if (n == 0) ctab[t] = (2.0f * bmax) / 126.0f;
    if (t == 0 && n < 2) scaleWS[n] = 0;
}

// ---------- pre 2: weight absmax ----------
__global__ void wmax_kernel(const float* __restrict__ Wap, const float* __restrict__ Wc,
                            int* __restrict__ scaleWS) {
    const int i = blockIdx.x * 256 + threadIdx.x;
    float m1 = fabsf(Wap[i]);
    float m2 = fabsf(Wc[i]);
    #pragma unroll
    for (int o = 1; o < 64; o <<= 1) {
        m1 = fmaxf(m1, __shfl_xor(m1, o));
        m2 = fmaxf(m2, __shfl_xor(m2, o));
    }
    __shared__ float r1[4], r2[4];
    const int wv = threadIdx.x >> 6, ln = threadIdx.x & 63;
    if (ln == 0) { r1[wv] = m1; r2[wv] = m2; }
    __syncthreads();
    if (threadIdx.x == 0) {
        const float a = fmaxf(fmaxf(r1[0], r1[1]), fmaxf(r1[2], r1[3]));
        const float b = fmaxf(fmaxf(r2[0], r2[1]), fmaxf(r2[2], r2[3]));
        atomicMax(&scaleWS[0], __float_as_int(a));
        atomicMax(&scaleWS[1], __float_as_int(b));
    }
}

// ---------- pre 3: quantize weights to i8, transposed to [m][k] ----------
__global__ void wquant_kernel(const float* __restrict__ Wap, const float* __restrict__ Wc,
                              const int* __restrict__ scaleWS,
                              char* __restrict__ qWap, char* __restrict__ qWc) {
    const int m = blockIdx.x, k = threadIdx.x;
    const float q1 = 127.0f / __int_as_float(scaleWS[0]);
    const float q2 = 127.0f / __int_as_float(scaleWS[1]);
    qWap[m * 256 + k] = (char)(int)rintf(Wap[k * 256 + m] * q1);
    qWc[m * 256 + k]  = (char)(int)rintf(Wc[k * 256 + m] * q2);
}

// ---------- main: 16 rows/block, 8 waves, 2 barriers/step, 2 blocks/CU ----------
__global__ __launch_bounds__(512, 4) void rnn_kernel(
    const float* __restrict__ cue, const float* __restrict__ ec5_init,
    const char* __restrict__ qWap, const char* __restrict__ qWc,
    const int* __restrict__ scaleWS, const float* __restrict__ Wact,
    const float* __restrict__ Atab, const float* __restrict__ Etab,
    const float* __restrict__ ctab, float* __restrict__ out)
{
    __shared__ __align__(16) char sStage[8192 + 1024];  // sE@0, sC@4096, sPart@8192
    float* sPart = (float*)&sStage[8192];

    const int tid  = threadIdx.x;
    const int wave = tid >> 6;
    const int lane = tid & 63;
    const int quad = lane >> 4;
    const int L    = lane & 15;
    const int wb   = wave * 32;
    const int row0 = blockIdx.x * 16;

    const float sW1 = __int_as_float(scaleWS[0]);
    const float sW2 = __int_as_float(scaleWS[1]);
    const float nf1 = -sW1 / (127.0f * 127.0f);   // gemm1 dequant (ec3 scale 127)
    const float sWc127 = sW2 / 127.0f;

    // weight A-frags: lane (quad,L) holds W^T[m=wb+mt*16+L][k=c*64+quad*16+j]
    i32x4 WA[2][4], WC[2][4];
    #pragma unroll
    for (int mt = 0; mt < 2; ++mt) {
        const int m = wb + mt * 16 + L;
        #pragma unroll
        for (int c = 0; c < 4; ++c) {
            WA[mt][c] = *(const i32x4*)&qWap[m * 256 + c * 64 + quad * 16];
            WC[mt][c] = *(const i32x4*)&qWc[m * 256 + c * 64 + quad * 16];
        }
    }

    // persistent zero C-quad: first MFMA reads it instead of zero-initing AGPRs
    i32x4 kZero;
    #pragma unroll
    for (int r = 0; r < 4; ++r) kZero[r] = 0;

    // state fp32 (C/D layout): lane (quad,L) holds row row0+L, feats wb+mt*16+quad*4+r
    float e5[2][4], e3[2][4];
    #pragma unroll
    for (int mt = 0; mt < 2; ++mt) {
        const f32x4 a = *(const f32x4*)&ec5_init[(row0 + L) * 256 + wb + mt * 16 + quad * 4];
        #pragma unroll
        for (int r = 0; r < 4; ++r) { e5[mt][r] = a[r]; e3[mt][r] = 0.f; }
    }

    // XOR-swizzled stage addresses (16B blocks xor'd with row L)
    int rd[4], wr[2];
    #pragma unroll
    for (int c = 0; c < 4; ++c)
        rd[c] = L * 256 + (((4 * c + quad) ^ L) << 4);
    #pragma unroll
    for (int mt = 0; mt < 2; ++mt)
        wr[mt] = L * 256 + (((wave * 2 + mt) ^ L) << 4) + quad * 4;

    auto gemm = [&](int sb, const i32x4 (&W)[2][4], i32x4 (&acc)[2]) {
        #pragma unroll
        for (int c = 0; c < 4; ++c) {
            const i32x4 bf = *(const i32x4*)&sStage[sb + rd[c]];
            if (c == 0) {
                acc[0] = __builtin_amdgcn_mfma_i32_16x16x64_i8(W[0][c], bf, kZero, 0, 0, 0);
                acc[1] = __builtin_amdgcn_mfma_i32_16x16x64_i8(W[1][c], bf, kZero, 0, 0, 0);
            } else {
                acc[0] = __builtin_amdgcn_mfma_i32_16x16x64_i8(W[0][c], bf, acc[0], 0, 0, 0);
                acc[1] = __builtin_amdgcn_mfma_i32_16x16x64_i8(W[1][c], bf, acc[1], 0, 0, 0);
            }
        }
    };

    // desync: co-resident blocks (ids ~256 apart) anti-phase their barriers
    if ((blockIdx.x >> 8) & 1) {
        __builtin_amdgcn_s_sleep(15);
        __builtin_amdgcn_s_sleep(15);
    }

    // ===== t = 0 (peeled): ec3=0 -> sigmoid = 0.5 exactly; ca1 row-independent =====
    {
        #pragma unroll
        for (int mt = 0; mt < 2; ++mt) {
            const int f0 = wb + mt * 16 + quad * 4;
            const f32x4 av = *(const f32x4*)&Atab[f0];
            const f32x4 ev = *(const f32x4*)&Etab[f0];
            unsigned dw = 0;
            #pragma unroll
            for (int r = 0; r < 4; ++r) {
                const float v = fmaxf(fmaf(av[r], 0.5f, ev[r]), 0.0f);
                dw |= ((unsigned)v) << (8 * r);
            }
            *(unsigned*)&sStage[4096 + wr[mt]] = dw;   // q(ca1_0)
        }
        __syncthreads();
        const float f2 = ctab[0] * sWc127;
        i32x4 acc2[2];
        gemm(4096, WC, acc2);
        #pragma unroll
        for (int mt = 0; mt < 2; ++mt) {
            const f32x4 cv = *(const f32x4*)&cue[(row0 + L) * 256 + wb + mt * 16 + quad * 4];
            unsigned dw = 0;
            #pragma unroll
            for (int r = 0; r < 4; ++r) {
                const float n5 = __builtin_amdgcn_fmed3f(
                    fmaf((float)acc2[mt][r], f2, e5[mt][r]), 0.0f, 1.0f);
                const float n3 = __builtin_amdgcn_fmed3f(cv[r], 0.0f, 1.0f);  // ec3_prev=0
                e5[mt][r] = n5; e3[mt][r] = n3;
                dw |= ((unsigned)fmaf(n3, 127.0f, 0.5f)) << (8 * r);
            }
            *(unsigned*)&sStage[wr[mt]] = dw;   // q(ec3)
        }
        __syncthreads();
    }

    // ===== steady state t = 1..98: 2 phases, 2 barriers, unroll x2 =====
    #pragma unroll 2
    for (int t = 1; t <= 98; ++t) {
        f32x4 avc[2], evc[2];
        #pragma unroll
        for (int mt = 0; mt < 2; ++mt) {
            const int f0 = t * 256 + wb + mt * 16 + quad * 4;
            avc[mt] = *(const f32x4*)&Atab[f0];
            evc[mt] = *(const f32x4*)&Etab[f0];
        }
        const float f2 = ctab[t] * sWc127;

        // Phase A: G1 (sE -> acc) + e1 (-> sC)
        i32x4 acc[2];
        gemm(0, WA, acc);
        #pragma unroll
        for (int mt = 0; mt < 2; ++mt) {
            unsigned dw = 0;
            #pragma unroll
            for (int r = 0; r < 4; ++r) {
                const float s = __builtin_amdgcn_rcpf(1.0f + __expf((float)acc[mt][r] * nf1));
                const float v = fmaxf(fmaf(avc[mt][r], s, evc[mt][r]), 0.0f);
                dw |= ((unsigned)v) << (8 * r);
            }
            *(unsigned*)&sStage[4096 + wr[mt]] = dw;
        }
        __syncthreads();

        // Phase B: G2 (sC -> acc2) + e2 (-> sE, state update)
        i32x4 acc2[2];
        gemm(4096, WC, acc2);
        #pragma unroll
        for (int mt = 0; mt < 2; ++mt) {
            unsigned dw = 0;
            #pragma unroll
            for (int r = 0; r < 4; ++r) {
                const float n5 = __builtin_amdgcn_fmed3f(
                    fmaf((float)acc2[mt][r], f2, e5[mt][r]), 0.0f, 1.0f);
                const float n3 = n5 * e3[mt][r];   // both in [0,1]: clip redundant
                e5[mt][r] = n5; e3[mt][r] = n3;
                dw |= ((unsigned)fmaf(n3, 127.0f, 0.5f)) << (8 * r);
            }
            *(unsigned*)&sStage[wr[mt]] = dw;
        }
        __syncthreads();
    }

    // ===== t = 99 (peeled): G1 + e1 + Waction partial dot =====
    {
        i32x4 acc[2];
        gemm(0, WA, acc);
        const float ct = ctab[99];
        float p0 = 0.f, p1 = 0.f;
        #pragma unroll
        for (int mt = 0; mt < 2; ++mt) {
            const int f0 = wb + mt * 16 + quad * 4;
            const f32x4 av = *(const f32x4*)&Atab[99 * 256 + f0];
            const f32x4 ev = *(const f32x4*)&Etab[99 * 256 + f0];
            const f32x4 w0 = *(const f32x4*)&Wact[f0 * 2];       // feats f0, f0+1
            const f32x4 w1 = *(const f32x4*)&Wact[f0 * 2 + 4];   // feats f0+2, f0+3
            #pragma unroll
            for (int r = 0; r < 4; ++r) {
                const float s = __builtin_amdgcn_rcpf(1.0f + __expf((float)acc[mt][r] * nf1));
                const float c = fmaxf(fmaf(av[r], s, ev[r]) - 0.5f, 0.0f) * ct;
                const float wa = (r & 2) ? ((r & 1) ? w1[2] : w1[0]) : ((r & 1) ? w0[2] : w0[0]);
                const float wb2 = (r & 2) ? ((r & 1) ? w1[3] : w1[1]) : ((r & 1) ? w0[3] : w0[1]);
                p0 = fmaf(c, wa, p0);
                p1 = fmaf(c, wb2, p1);
            }
        }
        p0 += __shfl_xor(p0, 16); p0 += __shfl_xor(p0, 32);
        p1 += __shfl_xor(p1, 16); p1 += __shfl_xor(p1, 32);
        if (quad == 0) {
            sPart[(L * 2 + 0) * 8 + wave] = p0;
            sPart[(L * 2 + 1) * 8 + wave] = p1;
        }
    }
    __syncthreads();
    if (tid < 32) {
        float s = 0.f;
        #pragma unroll
        for (int g = 0; g < 8; ++g) s += sPart[tid * 8 + g];
        out[row0 * 2 + tid] = s;
    }
}

extern "C" void kernel_launch(void* const* d_in, const int* in_sizes, int n_in,
                              void* d_out, int out_size, void* d_ws, size_t ws_size,
                              hipStream_t stream) {
    const float* cue      = (const float*)d_in[0];
    const float* ec5_init = (const float*)d_in[1];
    const float* Wapical  = (const float*)d_in[2];
    const float* Wbasal   = (const float*)d_in[3];
    const float* Wca1ec5  = (const float*)d_in[4];
    const float* Waction  = (const float*)d_in[5];
    const float* ca1bias  = (const float*)d_in[6];
    float* out = (float*)d_out;

    float* Atab = (float*)d_ws;                  // 25600 f32
    float* Etab = Atab + 25600;                  // 25600 f32
    float* ctab = Etab + 25600;                  // 100 f32
    int*   scaleWS = (int*)(ctab + 100);         // 4 ints
    char*  qWap = (char*)(scaleWS + 4);          // 65536 B
    char*  qWc  = qWap + 65536;                  // 65536 B

    basal2_kernel<<<100, 256, 0, stream>>>(Wbasal, ca1bias, Atab, Etab, ctab, scaleWS);
    wmax_kernel<<<256, 256, 0, stream>>>(Wapical, Wca1ec5, scaleWS);
    wquant_kernel<<<256, 256, 0, stream>>>(Wapical, Wca1ec5, scaleWS, qWap, qWc);
    rnn_kernel<<<2048, 512, 0, stream>>>(cue, ec5_init, qWap, qWc, scaleWS, Waction,
                                         Atab, Etab, ctab, out);
}